// Round 1
// baseline (2268.366 us; speedup 1.0000x reference)
//
#include <hip/hip_runtime.h>
#include <hip/hip_bf16.h>

#define NN 60000
#define NE 600000
#define DD 128
#define NTOT (NE + NN)
#define NB ((NN + 255) / 256)   // 235 blocks for scan
#define NBK1 ((NN + 63) / 64)   // 938 blocks for gemm
#define FILLB ((NTOT + 255) / 256)  // 2579
#define GGRID ((NN + 3) / 4)    // 15000 gather blocks (4 nodes each)

typedef __attribute__((ext_vector_type(8))) short short8;
typedef __attribute__((ext_vector_type(4))) float f32x4;

__device__ __forceinline__ unsigned short f2bf(float f) {
    unsigned int u = __float_as_uint(f);
    unsigned int r = (u + 0x7FFF + ((u >> 16) & 1)) >> 16;  // RNE
    return (unsigned short)r;
}
__device__ __forceinline__ float bflo(unsigned int u) { return __uint_as_float(u << 16); }
__device__ __forceinline__ float bfhi(unsigned int u) { return __uint_as_float(u & 0xFFFF0000u); }

// ---- degree (edges only; +1 self-loop folded in later) ----
__global__ __launch_bounds__(256) void deg_kernel(const int* __restrict__ dst, int* __restrict__ deg) {
    int e = blockIdx.x * 256 + threadIdx.x;
    if (e < NE) atomicAdd(&deg[dst[e]], 1);
}

// ---- scanA: per-block sums of (deg+1), fused dinv, fused scanB via last-block ----
__global__ __launch_bounds__(256) void scanA_kernel(const int* __restrict__ deg, int* __restrict__ partials,
                                                    float* __restrict__ dinv,
                                                    int* __restrict__ blockoff,
                                                    int* __restrict__ rowptr,
                                                    int* __restrict__ cnt) {
    __shared__ int lds[256];
    __shared__ int lastflag;
    int i = blockIdx.x * 256 + threadIdx.x;
    int t = threadIdx.x;
    int dv = (i < NN) ? deg[i] : 0;
    if (i < NN) dinv[i] = rsqrtf((float)(dv + 1));
    int v = (i < NN) ? dv + 1 : 0;
    lds[t] = v;
    __syncthreads();
    for (int off = 128; off > 0; off >>= 1) {
        if (t < off) lds[t] += lds[t + off];
        __syncthreads();
    }
    if (t == 0) {
        __hip_atomic_store(&partials[blockIdx.x], lds[0], __ATOMIC_RELEASE, __HIP_MEMORY_SCOPE_AGENT);
        int old = __hip_atomic_fetch_add(cnt, 1, __ATOMIC_ACQ_REL, __HIP_MEMORY_SCOPE_AGENT);
        lastflag = (old == (int)gridDim.x - 1);
    }
    __syncthreads();
    if (!lastflag) return;
    // ---- inlined scanB (runs in the last-arriving block only) ----
    int pv = (t < NB) ? __hip_atomic_load(&partials[t], __ATOMIC_RELAXED, __HIP_MEMORY_SCOPE_AGENT) : 0;
    __syncthreads();
    lds[t] = pv;
    __syncthreads();
    for (int off = 1; off < 256; off <<= 1) {
        int u = (t >= off) ? lds[t - off] : 0;
        __syncthreads();
        lds[t] += u;
        __syncthreads();
    }
    if (t < NB) blockoff[t] = lds[t] - pv;  // exclusive
    if (t == 0) rowptr[NN] = NTOT;
}

__global__ __launch_bounds__(256) void scanC_kernel(const int* __restrict__ deg,
                                                    const int* __restrict__ blockoff,
                                                    int* __restrict__ rowptr) {
    __shared__ int lds[256];
    int i = blockIdx.x * 256 + threadIdx.x;
    int t = threadIdx.x;
    int v = (i < NN) ? deg[i] + 1 : 0;
    lds[t] = v;
    __syncthreads();
    for (int off = 1; off < 256; off <<= 1) {
        int u = (t >= off) ? lds[t - off] : 0;
        __syncthreads();
        lds[t] += u;
        __syncthreads();
    }
    if (i < NN) rowptr[i] = blockoff[blockIdx.x] + lds[t] - v;
}

// ---- CSR fill (blocks < FILLB) fused with W convert (blocks >= FILLB) ----
__global__ __launch_bounds__(256) void fillw_kernel(const int* __restrict__ src, const int* __restrict__ dst,
                                                    const int* __restrict__ rowptr, int* __restrict__ cursor,
                                                    const float* __restrict__ dinv,
                                                    int2* __restrict__ csr,
                                                    const float* __restrict__ W0, const float* __restrict__ W1,
                                                    const float* __restrict__ W2, unsigned short* __restrict__ Wsw) {
    if (blockIdx.x < FILLB) {
        int e = blockIdx.x * 256 + threadIdx.x;
        if (e >= NTOT) return;
        int s, t;
        if (e < NE) { s = src[e]; t = dst[e]; }
        else { s = t = e - NE; }
        int pos = atomicAdd(&cursor[t], 1);
        int2 rec;
        rec.x = s;
        rec.y = __float_as_int(dinv[s] * dinv[t]);
        csr[rowptr[t] + pos] = rec;
    } else {
        int idx = (blockIdx.x - FILLB) * 256 + threadIdx.x;  // 3 * 32 frags * 64 lanes = 6144
        if (idx >= 3 * 32 * 64) return;
        int L = idx >> 11;
        int rem = idx & 2047;
        int frag = rem >> 6;         // 0..31  (kc*8 + nt)
        int lane = rem & 63;
        int kc = frag >> 3, nt = frag & 7;
        int m = lane & 15, q = lane >> 4;
        int n = nt * 16 + m;
        int k0 = kc * 32 + q * 8;
        const float* W = (L == 0) ? W0 : (L == 1) ? W1 : W2;
        unsigned int p[4];
#pragma unroll
        for (int j = 0; j < 4; j++) {
            unsigned int b0 = f2bf(W[(size_t)(k0 + 2 * j) * DD + n]);
            unsigned int b1 = f2bf(W[(size_t)(k0 + 2 * j + 1) * DD + n]);
            p[j] = b0 | (b1 << 16);
        }
        uint4 o; o.x = p[0]; o.y = p[1]; o.z = p[2]; o.w = p[3];
        *(uint4*)(Wsw + ((size_t)L * 2048 + (size_t)frag * 64 + lane) * 8) = o;
    }
}

// ---- MFMA GEMM (R11 coalesced design, unchanged) ----
template <bool BF16IN>
__global__ __launch_bounds__(256) void gemm_mfma_kernel(const void* __restrict__ Ain,
                                                        const unsigned short* __restrict__ Wsw,
                                                        const float* __restrict__ normp,
                                                        unsigned short* __restrict__ C) {
    __shared__ unsigned short Atile[64 * 128];  // 16 KB, swizzled 16B chunks
    __shared__ float rep[4][16][68];            // 17.4 KB, per-wave repack
    int tid = threadIdx.x;
    int wslot = tid >> 6;
    int l = tid & 63;
    int m = l & 15;
    int q = l >> 4;
    int rblk = blockIdx.x * 64;

#pragma unroll
    for (int p = 0; p < 4; p++) {
        int rowl = p * 16 + (tid >> 4);
        int c = tid & 15;
        int row = min(rblk + rowl, NN - 1);
        float a[8];
        if (BF16IN) {
            uint4 u = *(const uint4*)((const unsigned short*)Ain + (size_t)row * DD + c * 8);
            a[0] = bflo(u.x); a[1] = bfhi(u.x); a[2] = bflo(u.y); a[3] = bfhi(u.y);
            a[4] = bflo(u.z); a[5] = bfhi(u.z); a[6] = bflo(u.w); a[7] = bfhi(u.w);
        } else {
            const float* Af = (const float*)Ain + (size_t)row * DD + c * 8;
            float4 x0 = *(const float4*)Af;
            float4 x1 = *(const float4*)(Af + 4);
            a[0] = x0.x; a[1] = x0.y; a[2] = x0.z; a[3] = x0.w;
            a[4] = x1.x; a[5] = x1.y; a[6] = x1.z; a[7] = x1.w;
        }
        if (normp) {
#pragma unroll
            for (int j = 0; j < 8; j++) {
                float v = fmaf(a[j], normp[c * 8 + j], normp[128 + c * 8 + j]);
                a[j] = (v >= 0.f) ? v : 0.01f * v;
            }
        }
        unsigned int w0 = f2bf(a[0]) | ((unsigned int)f2bf(a[1]) << 16);
        unsigned int w1 = f2bf(a[2]) | ((unsigned int)f2bf(a[3]) << 16);
        unsigned int w2 = f2bf(a[4]) | ((unsigned int)f2bf(a[5]) << 16);
        unsigned int w3 = f2bf(a[6]) | ((unsigned int)f2bf(a[7]) << 16);
        uint4 wv; wv.x = w0; wv.y = w1; wv.z = w2; wv.w = w3;
        *(uint4*)&Atile[rowl * 128 + ((c ^ (rowl & 15)) * 8)] = wv;
    }
    __syncthreads();

    f32x4 acc[8];
#pragma unroll
    for (int i = 0; i < 8; i++) acc[i] = (f32x4){0.f, 0.f, 0.f, 0.f};
    int rowl_w = wslot * 16 + m;
#pragma unroll
    for (int kc = 0; kc < 4; kc++) {
        short8 af = *(const short8*)&Atile[rowl_w * 128 + (((kc * 4 + q) ^ m) * 8)];
#pragma unroll
        for (int nt = 0; nt < 8; nt++) {
            short8 bf = *(const short8*)(Wsw + ((size_t)(kc * 8 + nt) * 64 + l) * 8);
            acc[nt] = __builtin_amdgcn_mfma_f32_16x16x32_bf16(af, bf, acc[nt], 0, 0, 0);
        }
    }

    int wrow0 = rblk + wslot * 16;
    int r2 = l >> 2, c2 = l & 3;
#pragma unroll
    for (int pass = 0; pass < 2; pass++) {
#pragma unroll
        for (int ntl = 0; ntl < 4; ntl++) {
            f32x4 a = acc[pass * 4 + ntl];
#pragma unroll
            for (int r = 0; r < 4; r++)
                rep[wslot][q * 4 + r][ntl * 16 + m] = a[r];
        }
        const float* tr = &rep[wslot][r2][c2 * 16];
        float4 v0 = *(const float4*)(tr);
        float4 v1 = *(const float4*)(tr + 4);
        float4 v2 = *(const float4*)(tr + 8);
        float4 v3 = *(const float4*)(tr + 12);
        uint4 oA, oB;
        oA.x = f2bf(v0.x) | ((unsigned int)f2bf(v0.y) << 16);
        oA.y = f2bf(v0.z) | ((unsigned int)f2bf(v0.w) << 16);
        oA.z = f2bf(v1.x) | ((unsigned int)f2bf(v1.y) << 16);
        oA.w = f2bf(v1.z) | ((unsigned int)f2bf(v1.w) << 16);
        oB.x = f2bf(v2.x) | ((unsigned int)f2bf(v2.y) << 16);
        oB.y = f2bf(v2.z) | ((unsigned int)f2bf(v2.w) << 16);
        oB.z = f2bf(v3.x) | ((unsigned int)f2bf(v3.y) << 16);
        oB.w = f2bf(v3.z) | ((unsigned int)f2bf(v3.w) << 16);
        int row = wrow0 + r2;
        if (row < NN) {
            unsigned short* cp = C + (size_t)row * DD + pass * 64 + c2 * 16;
            *(uint4*)cp = oA;
            *(uint4*)(cp + 8) = oB;
        }
    }
}

// ---- CSR gather (known-good core) + fused BN stats epilogue + last-block finalize ----
__global__ __launch_bounds__(256) void gather_kernel(const unsigned short* __restrict__ xw,
                                                     const int* __restrict__ rowptr,
                                                     const int2* __restrict__ csr,
                                                     unsigned short* __restrict__ agg,
                                                     float* __restrict__ accL,
                                                     int* __restrict__ cntL,
                                                     const float* __restrict__ g,
                                                     const float* __restrict__ be,
                                                     float* __restrict__ normp) {
    int tid = threadIdx.x;
    int wslot = tid >> 6;
    int l = tid & 63;
    int wid = blockIdx.x * 4 + wslot;   // grid exactly covers NN
    int beg = rowptr[wid], end = rowptr[wid + 1];
    float ax = 0.f, ay = 0.f;
    int i = beg;
    for (; i + 8 <= end; i += 8) {
        unsigned int u[8];
        float c[8];
#pragma unroll
        for (int j = 0; j < 8; j++) {
            int2 r = csr[i + j];
            u[j] = *(const unsigned int*)(xw + (size_t)r.x * DD + 2 * l);
            c[j] = __int_as_float(r.y);
        }
#pragma unroll
        for (int j = 0; j < 8; j++) {
            ax += bflo(u[j]) * c[j];
            ay += bfhi(u[j]) * c[j];
        }
    }
    for (; i + 2 <= end; i += 2) {
        int2 r0 = csr[i], r1 = csr[i + 1];
        unsigned int u0 = *(const unsigned int*)(xw + (size_t)r0.x * DD + 2 * l);
        unsigned int u1 = *(const unsigned int*)(xw + (size_t)r1.x * DD + 2 * l);
        float c0 = __int_as_float(r0.y), c1 = __int_as_float(r1.y);
        ax += bflo(u0) * c0 + bflo(u1) * c1;
        ay += bfhi(u0) * c0 + bfhi(u1) * c1;
    }
    if (i < end) {
        int2 r0 = csr[i];
        unsigned int u0 = *(const unsigned int*)(xw + (size_t)r0.x * DD + 2 * l);
        float c0 = __int_as_float(r0.y);
        ax += bflo(u0) * c0;
        ay += bfhi(u0) * c0;
    }
    ((unsigned int*)(agg + (size_t)wid * DD))[l] = (unsigned int)f2bf(ax) | ((unsigned int)f2bf(ay) << 16);

    // ---- BN stats epilogue: block-level sum/sumsq per feature ----
    __shared__ float ls[4][128];
    __shared__ float lq[4][128];
    __shared__ int lastflag;
    *(float2*)&ls[wslot][2 * l] = make_float2(ax, ay);
    *(float2*)&lq[wslot][2 * l] = make_float2(ax * ax, ay * ay);
    __syncthreads();
    float sv;
    if (tid < 128) {
        sv = ls[0][tid] + ls[1][tid] + ls[2][tid] + ls[3][tid];
    } else {
        int f = tid - 128;
        sv = lq[0][f] + lq[1][f] + lq[2][f] + lq[3][f];
    }
    atomicAdd(&accL[(size_t)(blockIdx.x & 31) * 256 + tid], sv);
    __syncthreads();   // waitcnt drains each wave's atomics before the counter bump
    if (tid == 0) {
        __threadfence();
        int old = __hip_atomic_fetch_add(cntL, 1, __ATOMIC_ACQ_REL, __HIP_MEMORY_SCOPE_AGENT);
        lastflag = (old == (int)gridDim.x - 1);
    }
    __syncthreads();
    if (!lastflag) return;

    // ---- last block: reduce 32 bucket rows, write scale/shift ----
    float tot = 0.f;
#pragma unroll
    for (int b = 0; b < 32; b++)
        tot += __hip_atomic_load(&accL[(size_t)b * 256 + tid], __ATOMIC_RELAXED, __HIP_MEMORY_SCOPE_AGENT);
    __shared__ float tbuf[256];
    tbuf[tid] = tot;
    __syncthreads();
    if (tid < 128) {
        const float invN = 1.0f / (float)NN;
        float mu = tbuf[tid] * invN;
        float var = tbuf[128 + tid] * invN - mu * mu;
        float sc = rsqrtf(var + 1e-5f) * g[tid];
        normp[tid] = sc;
        normp[128 + tid] = be[tid] - mu * sc;
    }
}

// ---- final: out_fp32 = bf16(agg)*scale+shift ----
__global__ __launch_bounds__(256) void bnapply_kernel(const unsigned short* __restrict__ h,
                                                      const float* __restrict__ normp,
                                                      float* __restrict__ out) {
    int idx = blockIdx.x * 256 + threadIdx.x;
    if (idx >= NN * DD / 4) return;
    int d = (idx * 4) & 127;
    uint2 u = *(const uint2*)(h + idx * 4);
    float4 sc = *(const float4*)&normp[d];
    float4 sh = *(const float4*)&normp[128 + d];
    float4 o;
    o.x = fmaf(bflo(u.x), sc.x, sh.x);
    o.y = fmaf(bfhi(u.x), sc.y, sh.y);
    o.z = fmaf(bflo(u.y), sc.z, sh.z);
    o.w = fmaf(bfhi(u.y), sc.w, sh.w);
    *(float4*)&out[idx * 4] = o;
}

extern "C" void kernel_launch(void* const* d_in, const int* in_sizes, int n_in,
                              void* d_out, int out_size, void* d_ws, size_t ws_size,
                              hipStream_t stream) {
    const float* x = (const float*)d_in[0];
    const int* ei = (const int*)d_in[1];
    const int* srcp = ei;
    const int* dstp = ei + NE;
    const float* w[3]  = {(const float*)d_in[2], (const float*)d_in[6],  (const float*)d_in[10]};
    const float* g[3]  = {(const float*)d_in[4], (const float*)d_in[8],  (const float*)d_in[12]};
    const float* be[3] = {(const float*)d_in[5], (const float*)d_in[9],  (const float*)d_in[13]};

    // workspace layout (~37 MB), all chunks 16-B aligned
    unsigned short* xwb  = (unsigned short*)d_ws;        // bf16 xw  [NN*DD]
    unsigned short* aggb = xwb + (size_t)NN * DD;        // bf16 agg [NN*DD]
    // ---- zeroed region (single memset): deg, cursor, cnts, acc ----
    int* deg    = (int*)(aggb + (size_t)NN * DD);        // [NN]
    int* cursor = deg + NN;                              // [NN]
    int* cnts   = cursor + NN;                           // [16]: 0..2 layer counters, 3 scan counter
    float* acc  = (float*)(cnts + 16);                   // [3][32][256] BN buckets
    // ---- end zeroed region ----
    int* rowptr = (int*)(acc + 3 * 32 * 256);            // [NN+16]
    float* dinv = (float*)(rowptr + NN + 16);            // [NN]
    float* ss   = dinv + NN;                             // [3*256] scale/shift per layer
    int* spart  = (int*)(ss + 3 * 256);                  // [256] scan partials
    int* blockoff = spart + 256;                         // [256]
    unsigned short* Wsw = (unsigned short*)(blockoff + 256);  // [3*128*128]
    int2* csr = (int2*)(Wsw + 3 * DD * DD);              // [NTOT] packed {src, coef}
    float* out = (float*)d_out;

    // ---- CSR build (once; edge_index constant across layers) ----
    size_t zbytes = (size_t)(2 * NN + 16) * sizeof(int) + (size_t)3 * 32 * 256 * sizeof(float);
    hipMemsetAsync(deg, 0, zbytes, stream);
    deg_kernel<<<(NE + 255) / 256, 256, 0, stream>>>(dstp, deg);
    scanA_kernel<<<NB, 256, 0, stream>>>(deg, spart, dinv, blockoff, rowptr, cnts + 3);
    scanC_kernel<<<NB, 256, 0, stream>>>(deg, blockoff, rowptr);
    fillw_kernel<<<FILLB + 24, 256, 0, stream>>>(srcp, dstp, rowptr, cursor, dinv, csr,
                                                 w[0], w[1], w[2], Wsw);

    for (int L = 0; L < 3; ++L) {
        const float* normp = (L == 0) ? nullptr : (ss + (L - 1) * 256);
        if (L == 0)
            gemm_mfma_kernel<false><<<NBK1, 256, 0, stream>>>(x, Wsw, normp, xwb);
        else
            gemm_mfma_kernel<true><<<NBK1, 256, 0, stream>>>(aggb, Wsw + (size_t)L * DD * DD, normp, xwb);
        gather_kernel<<<GGRID, 256, 0, stream>>>(xwb, rowptr, csr, aggb,
                                                 acc + (size_t)L * 32 * 256, cnts + L,
                                                 g[L], be[L], ss + L * 256);
    }
    bnapply_kernel<<<(NN * DD / 4 + 255) / 256, 256, 0, stream>>>(aggb, ss + 2 * 256, out);
}

// Round 2
// 379.418 us; speedup vs baseline: 5.9785x; 5.9785x over previous
//
#include <hip/hip_runtime.h>
#include <hip/hip_bf16.h>

#define NN 60000
#define NE 600000
#define DD 128
#define NTOT (NE + NN)
#define NB ((NN + 255) / 256)       // 235 blocks for scan
#define NBK1 ((NN + 63) / 64)       // 938 blocks for gemm
#define FILLB ((NTOT + 255) / 256)  // 2579
#define GGRID ((NN + 3) / 4)        // 15000 gather blocks (4 nodes each)
#define BNB 256                     // bnfuse blocks

typedef __attribute__((ext_vector_type(8))) short short8;
typedef __attribute__((ext_vector_type(4))) float f32x4;

__device__ __forceinline__ unsigned short f2bf(float f) {
    unsigned int u = __float_as_uint(f);
    unsigned int r = (u + 0x7FFF + ((u >> 16) & 1)) >> 16;  // RNE
    return (unsigned short)r;
}
__device__ __forceinline__ float bflo(unsigned int u) { return __uint_as_float(u << 16); }
__device__ __forceinline__ float bfhi(unsigned int u) { return __uint_as_float(u & 0xFFFF0000u); }

// ---- degree (edges only; +1 self-loop folded in later) ----
__global__ __launch_bounds__(256) void deg_kernel(const int* __restrict__ dst, int* __restrict__ deg) {
    int e = blockIdx.x * 256 + threadIdx.x;
    if (e < NE) atomicAdd(&deg[dst[e]], 1);
}

// ---- scanA: per-block sums of (deg+1), fused dinv, fused scanB via last-block (235 blocks: proven OK) ----
__global__ __launch_bounds__(256) void scanA_kernel(const int* __restrict__ deg, int* __restrict__ partials,
                                                    float* __restrict__ dinv,
                                                    int* __restrict__ blockoff,
                                                    int* __restrict__ rowptr,
                                                    int* __restrict__ cnt) {
    __shared__ int lds[256];
    __shared__ int lastflag;
    int i = blockIdx.x * 256 + threadIdx.x;
    int t = threadIdx.x;
    int dv = (i < NN) ? deg[i] : 0;
    if (i < NN) dinv[i] = rsqrtf((float)(dv + 1));
    int v = (i < NN) ? dv + 1 : 0;
    lds[t] = v;
    __syncthreads();
    for (int off = 128; off > 0; off >>= 1) {
        if (t < off) lds[t] += lds[t + off];
        __syncthreads();
    }
    if (t == 0) {
        __hip_atomic_store(&partials[blockIdx.x], lds[0], __ATOMIC_RELEASE, __HIP_MEMORY_SCOPE_AGENT);
        int old = __hip_atomic_fetch_add(cnt, 1, __ATOMIC_ACQ_REL, __HIP_MEMORY_SCOPE_AGENT);
        lastflag = (old == (int)gridDim.x - 1);
    }
    __syncthreads();
    if (!lastflag) return;
    // ---- inlined scanB (runs in the last-arriving block only) ----
    int pv = (t < NB) ? __hip_atomic_load(&partials[t], __ATOMIC_RELAXED, __HIP_MEMORY_SCOPE_AGENT) : 0;
    __syncthreads();
    lds[t] = pv;
    __syncthreads();
    for (int off = 1; off < 256; off <<= 1) {
        int u = (t >= off) ? lds[t - off] : 0;
        __syncthreads();
        lds[t] += u;
        __syncthreads();
    }
    if (t < NB) blockoff[t] = lds[t] - pv;  // exclusive
    if (t == 0) rowptr[NN] = NTOT;
}

__global__ __launch_bounds__(256) void scanC_kernel(const int* __restrict__ deg,
                                                    const int* __restrict__ blockoff,
                                                    int* __restrict__ rowptr) {
    __shared__ int lds[256];
    int i = blockIdx.x * 256 + threadIdx.x;
    int t = threadIdx.x;
    int v = (i < NN) ? deg[i] + 1 : 0;
    lds[t] = v;
    __syncthreads();
    for (int off = 1; off < 256; off <<= 1) {
        int u = (t >= off) ? lds[t - off] : 0;
        __syncthreads();
        lds[t] += u;
        __syncthreads();
    }
    if (i < NN) rowptr[i] = blockoff[blockIdx.x] + lds[t] - v;
}

// ---- CSR fill (blocks < FILLB) fused with W convert (blocks >= FILLB) ----
__global__ __launch_bounds__(256) void fillw_kernel(const int* __restrict__ src, const int* __restrict__ dst,
                                                    const int* __restrict__ rowptr, int* __restrict__ cursor,
                                                    const float* __restrict__ dinv,
                                                    int2* __restrict__ csr,
                                                    const float* __restrict__ W0, const float* __restrict__ W1,
                                                    const float* __restrict__ W2, unsigned short* __restrict__ Wsw) {
    if (blockIdx.x < FILLB) {
        int e = blockIdx.x * 256 + threadIdx.x;
        if (e >= NTOT) return;
        int s, t;
        if (e < NE) { s = src[e]; t = dst[e]; }
        else { s = t = e - NE; }
        int pos = atomicAdd(&cursor[t], 1);
        int2 rec;
        rec.x = s;
        rec.y = __float_as_int(dinv[s] * dinv[t]);
        csr[rowptr[t] + pos] = rec;
    } else {
        int idx = (blockIdx.x - FILLB) * 256 + threadIdx.x;  // 3 * 32 frags * 64 lanes = 6144
        if (idx >= 3 * 32 * 64) return;
        int L = idx >> 11;
        int rem = idx & 2047;
        int frag = rem >> 6;         // 0..31  (kc*8 + nt)
        int lane = rem & 63;
        int kc = frag >> 3, nt = frag & 7;
        int m = lane & 15, q = lane >> 4;
        int n = nt * 16 + m;
        int k0 = kc * 32 + q * 8;
        const float* W = (L == 0) ? W0 : (L == 1) ? W1 : W2;
        unsigned int p[4];
#pragma unroll
        for (int j = 0; j < 4; j++) {
            unsigned int b0 = f2bf(W[(size_t)(k0 + 2 * j) * DD + n]);
            unsigned int b1 = f2bf(W[(size_t)(k0 + 2 * j + 1) * DD + n]);
            p[j] = b0 | (b1 << 16);
        }
        uint4 o; o.x = p[0]; o.y = p[1]; o.z = p[2]; o.w = p[3];
        *(uint4*)(Wsw + ((size_t)L * 2048 + (size_t)frag * 64 + lane) * 8) = o;
    }
}

// ---- MFMA GEMM (R11 coalesced design, unchanged) ----
template <bool BF16IN>
__global__ __launch_bounds__(256) void gemm_mfma_kernel(const void* __restrict__ Ain,
                                                        const unsigned short* __restrict__ Wsw,
                                                        const float* __restrict__ normp,
                                                        unsigned short* __restrict__ C) {
    __shared__ unsigned short Atile[64 * 128];  // 16 KB, swizzled 16B chunks
    __shared__ float rep[4][16][68];            // 17.4 KB, per-wave repack
    int tid = threadIdx.x;
    int wslot = tid >> 6;
    int l = tid & 63;
    int m = l & 15;
    int q = l >> 4;
    int rblk = blockIdx.x * 64;

#pragma unroll
    for (int p = 0; p < 4; p++) {
        int rowl = p * 16 + (tid >> 4);
        int c = tid & 15;
        int row = min(rblk + rowl, NN - 1);
        float a[8];
        if (BF16IN) {
            uint4 u = *(const uint4*)((const unsigned short*)Ain + (size_t)row * DD + c * 8);
            a[0] = bflo(u.x); a[1] = bfhi(u.x); a[2] = bflo(u.y); a[3] = bfhi(u.y);
            a[4] = bflo(u.z); a[5] = bfhi(u.z); a[6] = bflo(u.w); a[7] = bfhi(u.w);
        } else {
            const float* Af = (const float*)Ain + (size_t)row * DD + c * 8;
            float4 x0 = *(const float4*)Af;
            float4 x1 = *(const float4*)(Af + 4);
            a[0] = x0.x; a[1] = x0.y; a[2] = x0.z; a[3] = x0.w;
            a[4] = x1.x; a[5] = x1.y; a[6] = x1.z; a[7] = x1.w;
        }
        if (normp) {
#pragma unroll
            for (int j = 0; j < 8; j++) {
                float v = fmaf(a[j], normp[c * 8 + j], normp[128 + c * 8 + j]);
                a[j] = (v >= 0.f) ? v : 0.01f * v;
            }
        }
        unsigned int w0 = f2bf(a[0]) | ((unsigned int)f2bf(a[1]) << 16);
        unsigned int w1 = f2bf(a[2]) | ((unsigned int)f2bf(a[3]) << 16);
        unsigned int w2 = f2bf(a[4]) | ((unsigned int)f2bf(a[5]) << 16);
        unsigned int w3 = f2bf(a[6]) | ((unsigned int)f2bf(a[7]) << 16);
        uint4 wv; wv.x = w0; wv.y = w1; wv.z = w2; wv.w = w3;
        *(uint4*)&Atile[rowl * 128 + ((c ^ (rowl & 15)) * 8)] = wv;
    }
    __syncthreads();

    f32x4 acc[8];
#pragma unroll
    for (int i = 0; i < 8; i++) acc[i] = (f32x4){0.f, 0.f, 0.f, 0.f};
    int rowl_w = wslot * 16 + m;
#pragma unroll
    for (int kc = 0; kc < 4; kc++) {
        short8 af = *(const short8*)&Atile[rowl_w * 128 + (((kc * 4 + q) ^ m) * 8)];
#pragma unroll
        for (int nt = 0; nt < 8; nt++) {
            short8 bf = *(const short8*)(Wsw + ((size_t)(kc * 8 + nt) * 64 + l) * 8);
            acc[nt] = __builtin_amdgcn_mfma_f32_16x16x32_bf16(af, bf, acc[nt], 0, 0, 0);
        }
    }

    int wrow0 = rblk + wslot * 16;
    int r2 = l >> 2, c2 = l & 3;
#pragma unroll
    for (int pass = 0; pass < 2; pass++) {
#pragma unroll
        for (int ntl = 0; ntl < 4; ntl++) {
            f32x4 a = acc[pass * 4 + ntl];
#pragma unroll
            for (int r = 0; r < 4; r++)
                rep[wslot][q * 4 + r][ntl * 16 + m] = a[r];
        }
        const float* tr = &rep[wslot][r2][c2 * 16];
        float4 v0 = *(const float4*)(tr);
        float4 v1 = *(const float4*)(tr + 4);
        float4 v2 = *(const float4*)(tr + 8);
        float4 v3 = *(const float4*)(tr + 12);
        uint4 oA, oB;
        oA.x = f2bf(v0.x) | ((unsigned int)f2bf(v0.y) << 16);
        oA.y = f2bf(v0.z) | ((unsigned int)f2bf(v0.w) << 16);
        oA.z = f2bf(v1.x) | ((unsigned int)f2bf(v1.y) << 16);
        oA.w = f2bf(v1.z) | ((unsigned int)f2bf(v1.w) << 16);
        oB.x = f2bf(v2.x) | ((unsigned int)f2bf(v2.y) << 16);
        oB.y = f2bf(v2.z) | ((unsigned int)f2bf(v2.w) << 16);
        oB.z = f2bf(v3.x) | ((unsigned int)f2bf(v3.y) << 16);
        oB.w = f2bf(v3.z) | ((unsigned int)f2bf(v3.w) << 16);
        int row = wrow0 + r2;
        if (row < NN) {
            unsigned short* cp = C + (size_t)row * DD + pass * 64 + c2 * 16;
            *(uint4*)cp = oA;
            *(uint4*)(cp + 8) = oB;
        }
    }
}

// ---- CSR gather: 1 node/wave, 2 edges per load instruction (half-wave rows), no tail ----
// No LDS, no atomics, no fences (R1 lesson: agent-scope fences at 15000-block scale = disaster).
__global__ __launch_bounds__(256) void gather_kernel(const unsigned short* __restrict__ xw,
                                                     const int* __restrict__ rowptr,
                                                     const int2* __restrict__ csr,
                                                     unsigned short* __restrict__ agg) {
    int tid = threadIdx.x;
    int wslot = tid >> 6;
    int l = tid & 63;
    int h = l >> 5;   // half: handles even (0) / odd (1) edges
    int s = l & 31;   // 8-byte chunk within row: features 4s..4s+3
    int wid = blockIdx.x * 4 + wslot;
    if (wid >= NN) return;
    int beg = rowptr[wid], end = rowptr[wid + 1];
    float a0 = 0.f, a1 = 0.f, a2 = 0.f, a3 = 0.f;
    for (int i = beg; i < end; i += 16) {
        int rx[8];
        float c[8];
#pragma unroll
        for (int j = 0; j < 8; j++) {
            int e = i + 2 * j + h;
            int2 rr = csr[min(e, end - 1)];   // clamped: dummy loads hit hot line
            rx[j] = rr.x;
            c[j] = (e < end) ? __int_as_float(rr.y) : 0.f;
        }
        uint2 u[8];
#pragma unroll
        for (int j = 0; j < 8; j++)
            u[j] = *(const uint2*)(xw + (size_t)rx[j] * DD + s * 4);
#pragma unroll
        for (int j = 0; j < 8; j++) {
            a0 += bflo(u[j].x) * c[j];
            a1 += bfhi(u[j].x) * c[j];
            a2 += bflo(u[j].y) * c[j];
            a3 += bfhi(u[j].y) * c[j];
        }
    }
    // combine even-edge (h=0) and odd-edge (h=1) partials
    a0 += __shfl_xor(a0, 32);
    a1 += __shfl_xor(a1, 32);
    a2 += __shfl_xor(a2, 32);
    a3 += __shfl_xor(a3, 32);
    if (h == 0) {
        uint2 o;
        o.x = (unsigned int)f2bf(a0) | ((unsigned int)f2bf(a1) << 16);
        o.y = (unsigned int)f2bf(a2) | ((unsigned int)f2bf(a3) << 16);
        *(uint2*)(agg + (size_t)wid * DD + s * 4) = o;
    }
}

// ---- BN stats: one kernel per layer. 256 blocks read agg, per-block partials,
// last-block (counter pattern at 256-block scale) reduces + writes scale/shift. ----
__global__ __launch_bounds__(256) void bnfuse_kernel(const unsigned short* __restrict__ h,
                                                     float* __restrict__ partial,
                                                     int* __restrict__ cnt,
                                                     const float* __restrict__ g,
                                                     const float* __restrict__ be,
                                                     float* __restrict__ normp) {
    int t = threadIdx.x;
    int rg = t >> 4;   // row within 16-row group
    int c  = t & 15;   // feature chunk: features 8c..8c+7
    float s[8], q[8];
#pragma unroll
    for (int j = 0; j < 8; j++) { s[j] = 0.f; q[j] = 0.f; }
    for (int row = blockIdx.x * 16 + rg; row < NN; row += 16 * BNB) {
        uint4 u = *(const uint4*)(h + (size_t)row * DD + c * 8);
        float v;
        v = bflo(u.x); s[0] += v; q[0] += v * v;
        v = bfhi(u.x); s[1] += v; q[1] += v * v;
        v = bflo(u.y); s[2] += v; q[2] += v * v;
        v = bfhi(u.y); s[3] += v; q[3] += v * v;
        v = bflo(u.z); s[4] += v; q[4] += v * v;
        v = bfhi(u.z); s[5] += v; q[5] += v * v;
        v = bflo(u.w); s[6] += v; q[6] += v * v;
        v = bfhi(u.w); s[7] += v; q[7] += v * v;
    }
    __shared__ float lds[2][16][128];  // 16 KB
#pragma unroll
    for (int j = 0; j < 8; j++) {
        lds[0][rg][c * 8 + j] = s[j];
        lds[1][rg][c * 8 + j] = q[j];
    }
    __syncthreads();
    {
        int f = t & 127, stat = t >> 7;
        float acc = 0.f;
#pragma unroll
        for (int r = 0; r < 16; r++) acc += lds[stat][r][f];
        partial[(size_t)blockIdx.x * 256 + t] = acc;  // (stat*128+f) == t, coalesced
    }
    __shared__ int lastflag;
    __syncthreads();  // barrier drains the partial stores before the release RMW
    if (t == 0) {
        int old = __hip_atomic_fetch_add(cnt, 1, __ATOMIC_ACQ_REL, __HIP_MEMORY_SCOPE_AGENT);
        lastflag = (old == BNB - 1);
    }
    __syncthreads();
    if (!lastflag) return;
    // last block: sum the 256 partial rows, finalize scale/shift
    float tot = 0.f;
#pragma unroll 8
    for (int r = 0; r < BNB; r++)
        tot += partial[(size_t)r * 256 + t];
    __shared__ float tbuf[256];
    tbuf[t] = tot;
    __syncthreads();
    if (t < 128) {
        const float invN = 1.0f / (float)NN;
        float mu = tbuf[t] * invN;
        float var = tbuf[128 + t] * invN - mu * mu;
        float sc = rsqrtf(var + 1e-5f) * g[t];
        normp[t] = sc;
        normp[128 + t] = be[t] - mu * sc;
    }
}

// ---- final: out_fp32 = bf16(agg)*scale+shift ----
__global__ __launch_bounds__(256) void bnapply_kernel(const unsigned short* __restrict__ h,
                                                      const float* __restrict__ normp,
                                                      float* __restrict__ out) {
    int idx = blockIdx.x * 256 + threadIdx.x;
    if (idx >= NN * DD / 4) return;
    int d = (idx * 4) & 127;
    uint2 u = *(const uint2*)(h + idx * 4);
    float4 sc = *(const float4*)&normp[d];
    float4 sh = *(const float4*)&normp[128 + d];
    float4 o;
    o.x = fmaf(bflo(u.x), sc.x, sh.x);
    o.y = fmaf(bfhi(u.x), sc.y, sh.y);
    o.z = fmaf(bflo(u.y), sc.z, sh.z);
    o.w = fmaf(bfhi(u.y), sc.w, sh.w);
    *(float4*)&out[idx * 4] = o;
}

extern "C" void kernel_launch(void* const* d_in, const int* in_sizes, int n_in,
                              void* d_out, int out_size, void* d_ws, size_t ws_size,
                              hipStream_t stream) {
    const float* x = (const float*)d_in[0];
    const int* ei = (const int*)d_in[1];
    const int* srcp = ei;
    const int* dstp = ei + NE;
    const float* w[3]  = {(const float*)d_in[2], (const float*)d_in[6],  (const float*)d_in[10]};
    const float* g[3]  = {(const float*)d_in[4], (const float*)d_in[8],  (const float*)d_in[12]};
    const float* be[3] = {(const float*)d_in[5], (const float*)d_in[9],  (const float*)d_in[13]};

    // workspace layout (~37 MB), all chunks 16-B aligned
    unsigned short* xwb  = (unsigned short*)d_ws;        // bf16 xw  [NN*DD]
    unsigned short* aggb = xwb + (size_t)NN * DD;        // bf16 agg [NN*DD]
    // ---- zeroed region (single memset): deg, cursor, cnts ----
    int* deg    = (int*)(aggb + (size_t)NN * DD);        // [NN]
    int* cursor = deg + NN;                              // [NN]
    int* cnts   = cursor + NN;                           // [16]: 0..2 bnfuse counters, 3 scan counter
    // ---- end zeroed region ----
    int* rowptr = cnts + 16;                             // [NN+16]
    float* dinv = (float*)(rowptr + NN + 16);            // [NN]
    float* ss   = dinv + NN;                             // [3*256] scale/shift per layer
    int* spart  = (int*)(ss + 3 * 256);                  // [256] scan partials
    int* blockoff = spart + 256;                         // [256]
    float* bnpart = (float*)(blockoff + 256);            // [BNB*256] bn partials (256 KB)
    unsigned short* Wsw = (unsigned short*)(bnpart + (size_t)BNB * 256);  // [3*128*128]
    int2* csr = (int2*)(Wsw + 3 * DD * DD);              // [NTOT] packed {src, coef}
    float* out = (float*)d_out;

    // ---- CSR build (once; edge_index constant across layers) ----
    hipMemsetAsync(deg, 0, (size_t)(2 * NN + 16) * sizeof(int), stream);
    deg_kernel<<<(NE + 255) / 256, 256, 0, stream>>>(dstp, deg);
    scanA_kernel<<<NB, 256, 0, stream>>>(deg, spart, dinv, blockoff, rowptr, cnts + 3);
    scanC_kernel<<<NB, 256, 0, stream>>>(deg, blockoff, rowptr);
    fillw_kernel<<<FILLB + 24, 256, 0, stream>>>(srcp, dstp, rowptr, cursor, dinv, csr,
                                                 w[0], w[1], w[2], Wsw);

    for (int L = 0; L < 3; ++L) {
        const float* normp = (L == 0) ? nullptr : (ss + (L - 1) * 256);
        if (L == 0)
            gemm_mfma_kernel<false><<<NBK1, 256, 0, stream>>>(x, Wsw, normp, xwb);
        else
            gemm_mfma_kernel<true><<<NBK1, 256, 0, stream>>>(aggb, Wsw + (size_t)L * DD * DD, normp, xwb);
        gather_kernel<<<GGRID, 256, 0, stream>>>(xwb, rowptr, csr, aggb);
        bnfuse_kernel<<<BNB, 256, 0, stream>>>(aggb, bnpart, cnts + L, g[L], be[L], ss + L * 256);
    }
    bnapply_kernel<<<(NN * DD / 4 + 255) / 256, 256, 0, stream>>>(aggb, ss + 2 * 256, out);
}